// Round 1
// baseline (15.751 us; speedup 1.0000x reference)
//
#include <hip/hip_runtime.h>

// CCNOT(c1=0, c2=1, t=2) on 12 qubits, batch 2048.
// Reference: out = state @ M, M a permutation matrix with M[i, tgt(i)] = 1,
// tgt(i) = i ^ (1<<9) iff bits 11 and 10 of i are set (big-endian qubit order).
// tgt is an involution => out[b, j] = state[b, tgt(j)]: a permuted copy.
//
// Permutation granularity is 512 floats (bit 9), so float4 loads/stores are
// both aligned and fully coalesced.

#define DIM 4096
#define BATCH 2048

__global__ __launch_bounds__(256) void ccnot_permute_kernel(
    const float4* __restrict__ in, float4* __restrict__ out, int total_vec4) {
    int stride = gridDim.x * blockDim.x;
    for (int v = blockIdx.x * blockDim.x + threadIdx.x; v < total_vec4; v += stride) {
        int e = v << 2;                 // element index
        int c = e & (DIM - 1);          // column within row
        int r = e >> 12;                // row (batch index)
        // controls: bits 11 and 10; target: bit 9
        int both = ((c >> 11) & (c >> 10)) & 1;
        int src_c = c ^ (both << 9);
        out[v] = in[(r << 10) + (src_c >> 2)];   // row*(4096/4) + src_c/4
    }
}

extern "C" void kernel_launch(void* const* d_in, const int* in_sizes, int n_in,
                              void* d_out, int out_size, void* d_ws, size_t ws_size,
                              hipStream_t stream) {
    const float4* state = (const float4*)d_in[0];
    float4* out = (float4*)d_out;
    int total_vec4 = (BATCH * DIM) / 4;  // 2,097,152
    dim3 block(256);
    dim3 grid(2048);
    ccnot_permute_kernel<<<grid, block, 0, stream>>>(state, out, total_vec4);
}

// Round 2
// 14.158 us; speedup vs baseline: 1.1125x; 1.1125x over previous
//
#include <hip/hip_runtime.h>

// CCNOT(c1=0, c2=1, t=2) on 12 qubits, batch 2048.
// out[b, j] = state[b, j ^ (1<<9)] iff bits 11 and 10 of j are set, else state[b, j].
// Pure permuted copy at 512-float granularity -> float4 stays aligned+coalesced.
//
// Structure: one block per row (2048 blocks x 256 threads = 8 blocks/CU,
// 32 waves/CU). Each thread: 4 independent float4 loads issued back-to-back,
// then 4 non-temporal stores (keep the write stream out of L2/L3 so the
// 32 MiB input stays cache-resident across graph replays).

#define DIM 4096
#define VEC4_PER_ROW (DIM / 4)  // 1024

typedef float f32x4 __attribute__((ext_vector_type(4)));

__global__ __launch_bounds__(256) void ccnot_permute_kernel(
    const f32x4* __restrict__ in, f32x4* __restrict__ out) {
    const int r = blockIdx.x;                       // row = batch index
    const f32x4* rin = in + r * VEC4_PER_ROW;
    f32x4* rout = out + r * VEC4_PER_ROW;
    const int tid = threadIdx.x;

    f32x4 vals[4];
#pragma unroll
    for (int k = 0; k < 4; ++k) {
        int v = k * 256 + tid;                      // float4 index within row, 0..1023
        int c = v << 2;                             // element column
        int both = ((c >> 11) & (c >> 10)) & 1;     // controls: bits 11 & 10
        int src_c = c ^ (both << 9);                // target: bit 9
        vals[k] = rin[src_c >> 2];
    }
#pragma unroll
    for (int k = 0; k < 4; ++k) {
        int v = k * 256 + tid;
        __builtin_nontemporal_store(vals[k], &rout[v]);
    }
}

extern "C" void kernel_launch(void* const* d_in, const int* in_sizes, int n_in,
                              void* d_out, int out_size, void* d_ws, size_t ws_size,
                              hipStream_t stream) {
    const f32x4* state = (const f32x4*)d_in[0];
    f32x4* out = (f32x4*)d_out;
    dim3 block(256);
    dim3 grid(2048);  // one block per batch row
    ccnot_permute_kernel<<<grid, block, 0, stream>>>(state, out);
}